// Round 5
// baseline (16037.628 us; speedup 1.0000x reference)
//
#include <hip/hip_runtime.h>
#include <stdint.h>
#include <stddef.h>

// TPGRUCell forward, MI355X gfx950.
// R5: combined per-batch recurrent matrices (Az/Ar/Ah) -> per-batch GEMV scan.
// R6: 512 WGs, L2-resident A slices.  R7: fused tag-publish exchange.
// R8 (this round): A is loop-invariant -- the scan re-streamed 96 MiB from L2
// every step (~46% of step time).  Hold the ENTIRE A-set in registers:
// 256 WGs x 512 thr x 48 uint4/thread = 96 MiB of VGPRs.  1 WG/CU
// (co-resident by construction), hot loop = pure VALU + LDS + tag exchange.
// Also: per-wave region spin (one less barrier), 2-cols-per-thread gates
// (no shuffle pack), out-stores after the tag (off critical path).

#define T_LEN 512
#define BATCH 64
#define DIN   512
#define DH    512
#define DT    128

typedef __attribute__((ext_vector_type(8))) short short8;
typedef __attribute__((ext_vector_type(4))) float f32x4;

static __device__ __forceinline__ float bf2f(unsigned short u) {
  unsigned v = ((unsigned)u) << 16;
  return __builtin_bit_cast(float, v);
}
static __device__ __forceinline__ unsigned short f2bf(float f) {
  unsigned v = __builtin_bit_cast(unsigned, f);
  unsigned r = (v + 0x7fffu + ((v >> 16) & 1u)) >> 16;
  return (unsigned short)r;
}
static __device__ __forceinline__ float sigmoid_f(float x) {
  return 1.f / (1.f + __expf(-x));
}
static __device__ __forceinline__ float tanh_f(float x) {
  float e = __expf(-2.f * fabsf(x));
  float t = (1.f - e) / (1.f + e);
  return copysignf(t, x);
}

template<bool F32>
static __device__ __forceinline__ void load8(const void* p, size_t off, unsigned short* d) {
  if (F32) {
    const float4* q = (const float4*)((const float*)p + off);
    float4 a = q[0], b = q[1];
    d[0] = f2bf(a.x); d[1] = f2bf(a.y); d[2] = f2bf(a.z); d[3] = f2bf(a.w);
    d[4] = f2bf(b.x); d[5] = f2bf(b.y); d[6] = f2bf(b.z); d[7] = f2bf(b.w);
  } else {
    *(uint4*)d = *(const uint4*)((const unsigned short*)p + off);
  }
}

// ---------------------------------------------------------------------------
// k_topic: the four topic@W projections, all f32.
// ---------------------------------------------------------------------------
__global__ __launch_bounds__(256) void k_topic(
    const float* __restrict__ topic,
    const float* __restrict__ Wzx,  // [128][1024]
    const float* __restrict__ Wzh,  // [128][1024]
    const float* __restrict__ Whx,  // [128][512]
    const float* __restrict__ Whh,  // [128][512]
    float* __restrict__ tzx, float* __restrict__ tzh,
    float* __restrict__ thx, float* __restrict__ thh)
{
  const int b = blockIdx.x;
  __shared__ float tp[DT];
  if (threadIdx.x < DT) tp[threadIdx.x] = topic[b * DT + threadIdx.x];
  __syncthreads();
  for (int c = threadIdx.x; c < 3072; c += 256) {
    const float* wp; float* op; int ld, cc;
    if (c < 1024)      { wp = Wzx; ld = 1024; cc = c;        op = &tzx[b*1024 + cc]; }
    else if (c < 2048) { wp = Wzh; ld = 1024; cc = c - 1024; op = &tzh[b*1024 + cc]; }
    else if (c < 2560) { wp = Whx; ld = 512;  cc = c - 2048; op = &thx[b*512  + cc]; }
    else               { wp = Whh; ld = 512;  cc = c - 2560; op = &thh[b*512  + cc]; }
    float acc = 0.f;
    #pragma unroll 4
    for (int k = 0; k < DT; ++k) acc += tp[k] * wp[(size_t)k * ld + cc];
    *op = acc;
  }
}

// ---------------------------------------------------------------------------
// gemm64 (phase 1): C(bf16) = A @ B, 64x64 tile, LDS-staged (verified).
// EPI==0: C *= rs[(row&63)*ldrs+col]; EPI==1: C += bias[col].
// ---------------------------------------------------------------------------
template<int EPI, bool AF32, bool BF32>
__global__ __launch_bounds__(256) void gemm64(
    const void* __restrict__ A, int lda,
    const void* __restrict__ B1, int ldb1,
    const float* __restrict__ rs1, int ldrs1,
    const float* __restrict__ bias,
    unsigned short* __restrict__ C, int ldc, int K)
{
  __shared__ unsigned short As[64][48];
  __shared__ unsigned short Bs[64][48];
  const int tid = threadIdx.x;
  const int n0 = blockIdx.x * 64;
  const int m0 = blockIdx.y * 64;
  const int wv = tid >> 6, lane = tid & 63;
  const int lh = lane & 15, q8 = (lane >> 4) * 8;
  const int arow = tid >> 2, acol = (tid & 3) * 8;
  const int brow = tid >> 3, bcol = (tid & 7) * 8;
  f32x4 acc[4] = {{0,0,0,0},{0,0,0,0},{0,0,0,0},{0,0,0,0}};

  for (int k0 = 0; k0 < K; k0 += 32) {
    unsigned short av[8], bv[8];
    load8<AF32>(A, (size_t)(m0 + arow) * lda + (k0 + acol), av);
    load8<BF32>(B1, (size_t)(k0 + brow) * ldb1 + (n0 + bcol), bv);
    __syncthreads();
    *(uint4*)(&As[arow][acol]) = *(const uint4*)av;
    #pragma unroll
    for (int i = 0; i < 8; ++i) Bs[bcol + i][brow] = bv[i];
    __syncthreads();
    short8 af = *(const short8*)(&As[wv * 16 + lh][q8]);
    #pragma unroll
    for (int nt = 0; nt < 4; ++nt) {
      short8 bf = *(const short8*)(&Bs[nt * 16 + lh][q8]);
      acc[nt] = __builtin_amdgcn_mfma_f32_16x16x32_bf16(af, bf, acc[nt], 0, 0, 0);
    }
  }

  #pragma unroll
  for (int nt = 0; nt < 4; ++nt) {
    #pragma unroll
    for (int r = 0; r < 4; ++r) {
      int row = m0 + wv * 16 + (lane >> 4) * 4 + r;
      int colc = nt * 16 + lh;
      float v = acc[nt][r];
      if (EPI == 0) v *= rs1[(size_t)(row & 63) * ldrs1 + (n0 + colc)];
      else          v += bias[n0 + colc];
      C[(size_t)row * ldc + (n0 + colc)] = f2bf(v);
    }
  }
}

// ---------------------------------------------------------------------------
// k_comb: per-batch combined matrix  C_b[i][c] = sum_k W1[i][off1+k] *
//         S[b][offS+k] * W2[k][c].   Grid (8, 8, 64), 256 thr, K = 512.
// ---------------------------------------------------------------------------
__global__ __launch_bounds__(256) void k_comb(
    const float* __restrict__ W1, int ld1, int off1,  // [512][ld1]
    const float* __restrict__ W2,                     // [512][512]
    const float* __restrict__ S, int ldS, int offS,   // [64][ldS]
    unsigned short* __restrict__ Cout)                // [64][512][512] bf16
{
  __shared__ unsigned short As[64][48];
  __shared__ unsigned short Bs[64][48];
  const int tid = threadIdx.x;
  const int n0 = blockIdx.x * 64;
  const int m0 = blockIdx.y * 64;
  const int b  = blockIdx.z;
  const int wv = tid >> 6, lane = tid & 63;
  const int lh = lane & 15, q8 = (lane >> 4) * 8;
  const int arow = tid >> 2, acol = (tid & 3) * 8;
  const int brow = tid >> 3, bcol = (tid & 7) * 8;
  const float* sv = S + (size_t)b * ldS + offS;
  f32x4 acc[4] = {{0,0,0,0},{0,0,0,0},{0,0,0,0},{0,0,0,0}};

  for (int k0 = 0; k0 < 512; k0 += 32) {
    unsigned short av[8], bv[8];
    {
      const float* p = W1 + (size_t)(m0 + arow) * ld1 + off1 + k0 + acol;
      float4 a = ((const float4*)p)[0], c2 = ((const float4*)p)[1];
      av[0]=f2bf(a.x); av[1]=f2bf(a.y); av[2]=f2bf(a.z); av[3]=f2bf(a.w);
      av[4]=f2bf(c2.x); av[5]=f2bf(c2.y); av[6]=f2bf(c2.z); av[7]=f2bf(c2.w);
    }
    {
      float sk = sv[k0 + brow];
      const float* p = W2 + (size_t)(k0 + brow) * 512 + n0 + bcol;
      float4 a = ((const float4*)p)[0], c2 = ((const float4*)p)[1];
      bv[0]=f2bf(a.x*sk); bv[1]=f2bf(a.y*sk); bv[2]=f2bf(a.z*sk); bv[3]=f2bf(a.w*sk);
      bv[4]=f2bf(c2.x*sk); bv[5]=f2bf(c2.y*sk); bv[6]=f2bf(c2.z*sk); bv[7]=f2bf(c2.w*sk);
    }
    __syncthreads();
    *(uint4*)(&As[arow][acol]) = *(const uint4*)av;
    #pragma unroll
    for (int i = 0; i < 8; ++i) Bs[bcol + i][brow] = bv[i];
    __syncthreads();
    short8 af = *(const short8*)(&As[wv * 16 + lh][q8]);
    #pragma unroll
    for (int nt = 0; nt < 4; ++nt) {
      short8 bf = *(const short8*)(&Bs[nt * 16 + lh][q8]);
      acc[nt] = __builtin_amdgcn_mfma_f32_16x16x32_bf16(af, bf, acc[nt], 0, 0, 0);
    }
  }

  #pragma unroll
  for (int nt = 0; nt < 4; ++nt) {
    #pragma unroll
    for (int r = 0; r < 4; ++r) {
      int row = m0 + wv * 16 + (lane >> 4) * 4 + r;
      int col = n0 + nt * 16 + lh;
      Cout[(size_t)b * 262144 + (size_t)row * 512 + col] = f2bf(acc[nt][r]);
    }
  }
}

static __device__ __forceinline__ void accum8(float* a, float hk, uint4 v) {
  unsigned u0 = v.x, u1 = v.y, u2 = v.z, u3 = v.w;
  a[0] += hk * __builtin_bit_cast(float, u0 << 16);
  a[1] += hk * __builtin_bit_cast(float, u0 & 0xffff0000u);
  a[2] += hk * __builtin_bit_cast(float, u1 << 16);
  a[3] += hk * __builtin_bit_cast(float, u1 & 0xffff0000u);
  a[4] += hk * __builtin_bit_cast(float, u2 << 16);
  a[5] += hk * __builtin_bit_cast(float, u2 & 0xffff0000u);
  a[6] += hk * __builtin_bit_cast(float, u3 << 16);
  a[7] += hk * __builtin_bit_cast(float, u3 & 0xffff0000u);
}

// ---------------------------------------------------------------------------
// k_scan4: 512-step scan, A-set fully register-resident.
// Grid = 256 WGs x 512 thr (1 WG/CU).  WG g: batch b = g>>2, col block
// w = g&3 (cols [w*128, w*128+128)).  Thread t: chunk = t&15 (8-col group),
// ph = t>>4 in [0,32) (k = ph + 32j, j in [0,16)).
// Preload: za/ra/va[16] uint4 = 768 B A-slice per thread (192 VGPR).
// Exchange: pub[2][64][4][80] u32 (64 data dwords = 128 bf16 cols + tag at
// [64]).  Producer: data stores -> vmcnt(0) -> tag = tm+1 (MALL bypass).
// Consumer: each h-loader wave spins on its own region tag (wave-uniform),
// loads, converts to LDS; one barrier.  Safety identical to R7 scheme.
// ---------------------------------------------------------------------------
__global__ __launch_bounds__(512, 2) void k_scan4(
    const unsigned short* __restrict__ Az,   // [64][512][512] bf16 (row=k, col=out)
    const unsigned short* __restrict__ Ar,
    const unsigned short* __restrict__ Ah,
    const unsigned short* __restrict__ ZRx,  // [T*64][1024] bf16
    const unsigned short* __restrict__ Hx,   // [T*64][512] bf16
    const float* __restrict__ mask,          // [T*64]
    unsigned* __restrict__ pub,              // [2][64][4][80] u32
    float* out)
{
  const int g = blockIdx.x;
  const int b = g >> 2;
  const int w = g & 3;
  const int c0 = w * 128;
  const int t = threadIdx.x;
  const int chunk = t & 15;
  const int ph = t >> 4;                 // [0,32)
  __shared__ float hs[512];
  __shared__ float part[32][16][25];     // [ph][chunk][3*8], padded stride 25
  __shared__ float red[384];             // [mat*128 + col]

  // ---- one-time A-slice preload into registers (loop-invariant!) ----
  const size_t abase = (size_t)b * 262144 + (size_t)ph * 512 + c0 + chunk * 8;
  uint4 za[16], ra[16], va[16];
  #pragma unroll
  for (int j = 0; j < 16; ++j) {
    za[j] = *(const uint4*)(Az + abase + (size_t)j * 32 * 512);
    ra[j] = *(const uint4*)(Ar + abase + (size_t)j * 32 * 512);
    va[j] = *(const uint4*)(Ah + abase + (size_t)j * 32 * 512);
  }

  unsigned* pubB0 = pub + (size_t)b * 320;         // parity 0: [4][80]
  unsigned* pubB1 = pub + (size_t)(64 + b) * 320;  // parity 1

  float hold0 = 0.f, hold1 = 0.f;  // master h (f32), cols c0+2t, c0+2t+1 (t<64)

  for (int tm = 0; tm < T_LEN; ++tm) {
    unsigned* pubC = (tm & 1) ? pubB1 : pubB0;   // consume (state after tm)
    unsigned* pubP = (tm & 1) ? pubB0 : pubB1;   // produce (state after tm+1)
    const size_t itb = (size_t)tm * BATCH + b;

    // gate-operand prefetch (cached loads; overlap with spin)
    unsigned p_zx = 0, p_rx = 0, p_hx = 0; float g_m = 0.f;
    if (t < 64) {
      int gc = c0 + 2 * t;
      p_zx = *(const unsigned*)(ZRx + itb * 1024 + gc);
      p_rx = *(const unsigned*)(ZRx + itb * 1024 + 512 + gc);
      p_hx = *(const unsigned*)(Hx + itb * 512 + gc);
      g_m  = mask[itb];
    }
    // per-wave region spin + h load (wave-uniform tag address)
    if (t < 256) {
      const unsigned* tagp = pubC + (t >> 6) * 80 + 64;
      while ((int)__hip_atomic_load(tagp, __ATOMIC_RELAXED, __HIP_MEMORY_SCOPE_AGENT) < tm)
        ;
      unsigned v = __hip_atomic_load(pubC + (t >> 6) * 80 + (t & 63),
                                     __ATOMIC_RELAXED, __HIP_MEMORY_SCOPE_AGENT);
      float2 hv;
      hv.x = bf2f((unsigned short)(v & 0xffffu));
      hv.y = bf2f((unsigned short)(v >> 16));
      *(float2*)(&hs[2 * t]) = hv;
    }
    __syncthreads();

    // GEMV: A from registers, h from LDS.  8 cols x 3 mats x 16 k-groups.
    float az[8] = {0,0,0,0,0,0,0,0};
    float ar[8] = {0,0,0,0,0,0,0,0};
    float av[8] = {0,0,0,0,0,0,0,0};
    #pragma unroll
    for (int j = 0; j < 16; ++j) {
      float hk = hs[ph + 32 * j];
      accum8(az, hk, za[j]);
      accum8(ar, hk, ra[j]);
      accum8(av, hk, va[j]);
    }
    #pragma unroll
    for (int e = 0; e < 8; ++e) {
      part[ph][chunk][e]      = az[e];
      part[ph][chunk][8 + e]  = ar[e];
      part[ph][chunk][16 + e] = av[e];
    }
    __syncthreads();

    // distributed reduction: 384 threads, one (mat,col) output each
    if (t < 384) {
      int m = t >> 7, c = t & 127;
      float s = 0.f;
      #pragma unroll
      for (int p = 0; p < 32; ++p) s += part[p][c >> 3][m * 8 + (c & 7)];
      red[(m << 7) + c] = s;
    }
    __syncthreads();

    // gates + publish: wave 0, 2 cols per thread (no shuffle pack)
    if (t < 64) {
      int c = 2 * t;
      float z0 = sigmoid_f(red[c]       + bf2f((unsigned short)(p_zx & 0xffffu)));
      float z1 = sigmoid_f(red[c + 1]   + bf2f((unsigned short)(p_zx >> 16)));
      float r0 = sigmoid_f(red[128 + c] + bf2f((unsigned short)(p_rx & 0xffffu)));
      float r1 = sigmoid_f(red[129 + c] + bf2f((unsigned short)(p_rx >> 16)));
      float hv0 = tanh_f(bf2f((unsigned short)(p_hx & 0xffffu)) + r0 * red[256 + c]);
      float hv1 = tanh_f(bf2f((unsigned short)(p_hx >> 16))     + r1 * red[257 + c]);
      float hn0 = (1.f - z0) * hv0 + z0 * hold0;
      float hn1 = (1.f - z1) * hv1 + z1 * hold1;
      hn0 = g_m * hn0 + (1.f - g_m) * hold0;
      hn1 = g_m * hn1 + (1.f - g_m) * hold1;
      hold0 = hn0; hold1 = hn1;
      // publish first (critical path), out-stores after the tag
      unsigned pk = (unsigned)f2bf(hn0) | ((unsigned)f2bf(hn1) << 16);
      __hip_atomic_store(pubP + w * 80 + t, pk,
                         __ATOMIC_RELAXED, __HIP_MEMORY_SCOPE_AGENT);
      asm volatile("s_waitcnt vmcnt(0)" ::: "memory");
      if (t == 0)
        __hip_atomic_store(pubP + w * 80 + 64, (unsigned)(tm + 1),
                           __ATOMIC_RELAXED, __HIP_MEMORY_SCOPE_AGENT);
      float2 o; o.x = hn0; o.y = hn1;
      *(float2*)(out + itb * 512 + c0 + c) = o;
      if (tm == T_LEN - 1)
        *(float2*)(out + (size_t)T_LEN * BATCH * 512 + (size_t)b * 512 + c0 + c) = o;
    }
    // waves 1..7 run ahead to the next step's spin; part/hs overwrite is
    // gated by the post-hs __syncthreads, which wave 0 joins after publish.
  }
}

// ---------------------------------------------------------------------------
extern "C" void kernel_launch(void* const* d_in, const int* in_sizes, int n_in,
                              void* d_out, int out_size, void* d_ws, size_t ws_size,
                              hipStream_t stream) {
  (void)in_sizes; (void)n_in; (void)out_size; (void)ws_size;
  const float* x        = (const float*)d_in[0];
  const float* topic    = (const float*)d_in[1];
  const float* mask     = (const float*)d_in[2];
  const float* W_x2zr   = (const float*)d_in[3];
  const float* W_tp2zrx = (const float*)d_in[4];
  const float* W_xtp2z  = (const float*)d_in[5];
  const float* b_xtp2z  = (const float*)d_in[6];
  const float* W_xtp2r  = (const float*)d_in[7];
  const float* b_xtp2r  = (const float*)d_in[8];
  const float* W_h2zr   = (const float*)d_in[9];
  const float* W_tp2zrh = (const float*)d_in[10];
  const float* W_htp2z  = (const float*)d_in[11];
  const float* W_htp2r  = (const float*)d_in[12];
  const float* W_x2h    = (const float*)d_in[13];
  const float* W_tp2hx  = (const float*)d_in[14];
  const float* W_xtp2h  = (const float*)d_in[15];
  const float* b_xtp2h  = (const float*)d_in[16];
  const float* W_h2h    = (const float*)d_in[17];
  const float* W_tp2hh  = (const float*)d_in[18];
  const float* W_htp2h  = (const float*)d_in[19];
  float* out = (float*)d_out;

  // ---- workspace carve (~194 MiB) ----
  char* w = (char*)d_ws;
  unsigned* pub = (unsigned*)w;      w += (size_t)2 * 64 * 4 * 80 * 4;  // 160 KB
  float* tzx = (float*)w;           w += (size_t)BATCH * 1024 * 4;
  float* tzh = (float*)w;           w += (size_t)BATCH * 1024 * 4;
  float* thx = (float*)w;           w += (size_t)BATCH * 512 * 4;
  float* thh = (float*)w;           w += (size_t)BATCH * 512 * 4;
  unsigned short* ZRxtp = (unsigned short*)w; w += (size_t)T_LEN * BATCH * 1024 * 2; // 64 MiB
  unsigned short* Hxtp  = (unsigned short*)w; w += (size_t)T_LEN * BATCH * 512 * 2;  // 32 MiB
  unsigned short* SCR   = (unsigned short*)w; w += (size_t)T_LEN * BATCH * 1024 * 2; // 64 MiB
  unsigned short* AhM   = (unsigned short*)w; w += (size_t)BATCH * 512 * 512 * 2;    // 32 MiB
  // SCR: phase-1 staging (ZRs, then Xhs), afterwards Az|Ar (2 x 32 MiB).
  unsigned short* ZRs = SCR;
  unsigned short* Xhs = SCR;
  unsigned short* AzM = SCR;
  unsigned short* ArM = SCR + (size_t)BATCH * 512 * 512;

  const int M = T_LEN * BATCH;  // 32768

  // pub zeroed: tags = 0 ("0 steps complete"), data = 0 (h0 = 0).
  hipMemsetAsync(pub, 0, (size_t)2 * 64 * 4 * 80 * 4, stream);

  // ---- phase 1: topic projections + x-side GEMM chain ----
  k_topic<<<BATCH, 256, 0, stream>>>(topic, W_tp2zrx, W_tp2zrh, W_tp2hx, W_tp2hh,
                                     tzx, tzh, thx, thh);
  gemm64<0, true, true><<<dim3(1024/64, M/64), 256, 0, stream>>>(
      x, DIN, W_x2zr, 1024, tzx, 1024, nullptr, ZRs, 1024, DIN);
  gemm64<1, false, true><<<dim3(512/64, M/64), 256, 0, stream>>>(
      ZRs, 1024, W_xtp2z, 512, nullptr, 0, b_xtp2z, ZRxtp, 1024, 512);
  gemm64<1, false, true><<<dim3(512/64, M/64), 256, 0, stream>>>(
      ZRs + 512, 1024, W_xtp2r, 512, nullptr, 0, b_xtp2r, ZRxtp + 512, 1024, 512);
  gemm64<0, true, true><<<dim3(512/64, M/64), 256, 0, stream>>>(
      x, DIN, W_x2h, 512, thx, 512, nullptr, Xhs, 512, DIN);
  gemm64<1, false, true><<<dim3(512/64, M/64), 256, 0, stream>>>(
      Xhs, 512, W_xtp2h, 512, nullptr, 0, b_xtp2h, Hxtp, 512, 512);

  // ---- combined per-batch recurrent matrices (overwrite SCR after use) ----
  k_comb<<<dim3(8, 8, 64), 256, 0, stream>>>(W_h2zr, 1024,   0, W_htp2z, tzh, 1024,   0, AzM);
  k_comb<<<dim3(8, 8, 64), 256, 0, stream>>>(W_h2zr, 1024, 512, W_htp2r, tzh, 1024, 512, ArM);
  k_comb<<<dim3(8, 8, 64), 256, 0, stream>>>(W_h2h,   512,   0, W_htp2h, thh,  512,   0, AhM);

  // ---- phase 2: register-resident GEMV scan, 256 WGs (1/CU) ----
  k_scan4<<<256, 512, 0, stream>>>(AzM, ArM, AhM, ZRxtp, Hxtp, mask,
                                   pub, out);
}

// Round 6
// 11550.220 us; speedup vs baseline: 1.3885x; 1.3885x over previous
//
#include <hip/hip_runtime.h>
#include <stdint.h>
#include <stddef.h>

// TPGRUCell forward, MI355X gfx950.
// R5: combined per-batch recurrent matrices (Az/Ar/Ah) -> per-batch GEMV scan.
// R6: 512 WGs, L2-resident A.  R7: fused tag-publish exchange (3.10 ms scan).
// R8: register-resident A FAILED: compiler rematerialized the loads (VGPR=128,
// FETCH back to 25 GB = per-step re-stream at 1 WG/CU = 14.9 ms).
// R9 (this round): enforce residency.
//  - za/ra (64 MiB chip-wide) in VGPRs as u32x4[16]x2 = 128 VGPR, made
//    UNREMATERIALIZABLE via asm volatile("":"+v"(...)) after the preload.
//  - va (Ah, 32 MiB) in LDS: [512][136] bf16 = 136 KB (pad row to 272 B =
//    1 bank-group rotation per row).  Loaded once before the loop.
//  - part[] staging shrunk 51->14 KB via intra-wave __shfl_xor(16/32)
//    pre-reduction so everything fits in 160 KiB LDS.
// Hot loop = pure VALU + LDS + tag exchange; A never touches L2 again.

#define T_LEN 512
#define BATCH 64
#define DIN   512
#define DH    512
#define DT    128

typedef __attribute__((ext_vector_type(8))) short short8;
typedef __attribute__((ext_vector_type(4))) float f32x4;
typedef __attribute__((ext_vector_type(4))) unsigned u32x4;

static __device__ __forceinline__ float bf2f(unsigned short u) {
  unsigned v = ((unsigned)u) << 16;
  return __builtin_bit_cast(float, v);
}
static __device__ __forceinline__ unsigned short f2bf(float f) {
  unsigned v = __builtin_bit_cast(unsigned, f);
  unsigned r = (v + 0x7fffu + ((v >> 16) & 1u)) >> 16;
  return (unsigned short)r;
}
static __device__ __forceinline__ float sigmoid_f(float x) {
  return 1.f / (1.f + __expf(-x));
}
static __device__ __forceinline__ float tanh_f(float x) {
  float e = __expf(-2.f * fabsf(x));
  float t = (1.f - e) / (1.f + e);
  return copysignf(t, x);
}

template<bool F32>
static __device__ __forceinline__ void load8(const void* p, size_t off, unsigned short* d) {
  if (F32) {
    const float4* q = (const float4*)((const float*)p + off);
    float4 a = q[0], b = q[1];
    d[0] = f2bf(a.x); d[1] = f2bf(a.y); d[2] = f2bf(a.z); d[3] = f2bf(a.w);
    d[4] = f2bf(b.x); d[5] = f2bf(b.y); d[6] = f2bf(b.z); d[7] = f2bf(b.w);
  } else {
    *(uint4*)d = *(const uint4*)((const unsigned short*)p + off);
  }
}

// ---------------------------------------------------------------------------
// k_topic: the four topic@W projections, all f32.
// ---------------------------------------------------------------------------
__global__ __launch_bounds__(256) void k_topic(
    const float* __restrict__ topic,
    const float* __restrict__ Wzx,  // [128][1024]
    const float* __restrict__ Wzh,  // [128][1024]
    const float* __restrict__ Whx,  // [128][512]
    const float* __restrict__ Whh,  // [128][512]
    float* __restrict__ tzx, float* __restrict__ tzh,
    float* __restrict__ thx, float* __restrict__ thh)
{
  const int b = blockIdx.x;
  __shared__ float tp[DT];
  if (threadIdx.x < DT) tp[threadIdx.x] = topic[b * DT + threadIdx.x];
  __syncthreads();
  for (int c = threadIdx.x; c < 3072; c += 256) {
    const float* wp; float* op; int ld, cc;
    if (c < 1024)      { wp = Wzx; ld = 1024; cc = c;        op = &tzx[b*1024 + cc]; }
    else if (c < 2048) { wp = Wzh; ld = 1024; cc = c - 1024; op = &tzh[b*1024 + cc]; }
    else if (c < 2560) { wp = Whx; ld = 512;  cc = c - 2048; op = &thx[b*512  + cc]; }
    else               { wp = Whh; ld = 512;  cc = c - 2560; op = &thh[b*512  + cc]; }
    float acc = 0.f;
    #pragma unroll 4
    for (int k = 0; k < DT; ++k) acc += tp[k] * wp[(size_t)k * ld + cc];
    *op = acc;
  }
}

// ---------------------------------------------------------------------------
// gemm64 (phase 1): C(bf16) = A @ B, 64x64 tile, LDS-staged (verified).
// EPI==0: C *= rs[(row&63)*ldrs+col]; EPI==1: C += bias[col].
// ---------------------------------------------------------------------------
template<int EPI, bool AF32, bool BF32>
__global__ __launch_bounds__(256) void gemm64(
    const void* __restrict__ A, int lda,
    const void* __restrict__ B1, int ldb1,
    const float* __restrict__ rs1, int ldrs1,
    const float* __restrict__ bias,
    unsigned short* __restrict__ C, int ldc, int K)
{
  __shared__ unsigned short As[64][48];
  __shared__ unsigned short Bs[64][48];
  const int tid = threadIdx.x;
  const int n0 = blockIdx.x * 64;
  const int m0 = blockIdx.y * 64;
  const int wv = tid >> 6, lane = tid & 63;
  const int lh = lane & 15, q8 = (lane >> 4) * 8;
  const int arow = tid >> 2, acol = (tid & 3) * 8;
  const int brow = tid >> 3, bcol = (tid & 7) * 8;
  f32x4 acc[4] = {{0,0,0,0},{0,0,0,0},{0,0,0,0},{0,0,0,0}};

  for (int k0 = 0; k0 < K; k0 += 32) {
    unsigned short av[8], bv[8];
    load8<AF32>(A, (size_t)(m0 + arow) * lda + (k0 + acol), av);
    load8<BF32>(B1, (size_t)(k0 + brow) * ldb1 + (n0 + bcol), bv);
    __syncthreads();
    *(uint4*)(&As[arow][acol]) = *(const uint4*)av;
    #pragma unroll
    for (int i = 0; i < 8; ++i) Bs[bcol + i][brow] = bv[i];
    __syncthreads();
    short8 af = *(const short8*)(&As[wv * 16 + lh][q8]);
    #pragma unroll
    for (int nt = 0; nt < 4; ++nt) {
      short8 bf = *(const short8*)(&Bs[nt * 16 + lh][q8]);
      acc[nt] = __builtin_amdgcn_mfma_f32_16x16x32_bf16(af, bf, acc[nt], 0, 0, 0);
    }
  }

  #pragma unroll
  for (int nt = 0; nt < 4; ++nt) {
    #pragma unroll
    for (int r = 0; r < 4; ++r) {
      int row = m0 + wv * 16 + (lane >> 4) * 4 + r;
      int colc = nt * 16 + lh;
      float v = acc[nt][r];
      if (EPI == 0) v *= rs1[(size_t)(row & 63) * ldrs1 + (n0 + colc)];
      else          v += bias[n0 + colc];
      C[(size_t)row * ldc + (n0 + colc)] = f2bf(v);
    }
  }
}

// ---------------------------------------------------------------------------
// k_comb: per-batch combined matrix  C_b[i][c] = sum_k W1[i][off1+k] *
//         S[b][offS+k] * W2[k][c].   Grid (8, 8, 64), 256 thr, K = 512.
// ---------------------------------------------------------------------------
__global__ __launch_bounds__(256) void k_comb(
    const float* __restrict__ W1, int ld1, int off1,  // [512][ld1]
    const float* __restrict__ W2,                     // [512][512]
    const float* __restrict__ S, int ldS, int offS,   // [64][ldS]
    unsigned short* __restrict__ Cout)                // [64][512][512] bf16
{
  __shared__ unsigned short As[64][48];
  __shared__ unsigned short Bs[64][48];
  const int tid = threadIdx.x;
  const int n0 = blockIdx.x * 64;
  const int m0 = blockIdx.y * 64;
  const int b  = blockIdx.z;
  const int wv = tid >> 6, lane = tid & 63;
  const int lh = lane & 15, q8 = (lane >> 4) * 8;
  const int arow = tid >> 2, acol = (tid & 3) * 8;
  const int brow = tid >> 3, bcol = (tid & 7) * 8;
  const float* sv = S + (size_t)b * ldS + offS;
  f32x4 acc[4] = {{0,0,0,0},{0,0,0,0},{0,0,0,0},{0,0,0,0}};

  for (int k0 = 0; k0 < 512; k0 += 32) {
    unsigned short av[8], bv[8];
    {
      const float* p = W1 + (size_t)(m0 + arow) * ld1 + off1 + k0 + acol;
      float4 a = ((const float4*)p)[0], c2 = ((const float4*)p)[1];
      av[0]=f2bf(a.x); av[1]=f2bf(a.y); av[2]=f2bf(a.z); av[3]=f2bf(a.w);
      av[4]=f2bf(c2.x); av[5]=f2bf(c2.y); av[6]=f2bf(c2.z); av[7]=f2bf(c2.w);
    }
    {
      float sk = sv[k0 + brow];
      const float* p = W2 + (size_t)(k0 + brow) * 512 + n0 + bcol;
      float4 a = ((const float4*)p)[0], c2 = ((const float4*)p)[1];
      bv[0]=f2bf(a.x*sk); bv[1]=f2bf(a.y*sk); bv[2]=f2bf(a.z*sk); bv[3]=f2bf(a.w*sk);
      bv[4]=f2bf(c2.x*sk); bv[5]=f2bf(c2.y*sk); bv[6]=f2bf(c2.z*sk); bv[7]=f2bf(c2.w*sk);
    }
    __syncthreads();
    *(uint4*)(&As[arow][acol]) = *(const uint4*)av;
    #pragma unroll
    for (int i = 0; i < 8; ++i) Bs[bcol + i][brow] = bv[i];
    __syncthreads();
    short8 af = *(const short8*)(&As[wv * 16 + lh][q8]);
    #pragma unroll
    for (int nt = 0; nt < 4; ++nt) {
      short8 bf = *(const short8*)(&Bs[nt * 16 + lh][q8]);
      acc[nt] = __builtin_amdgcn_mfma_f32_16x16x32_bf16(af, bf, acc[nt], 0, 0, 0);
    }
  }

  #pragma unroll
  for (int nt = 0; nt < 4; ++nt) {
    #pragma unroll
    for (int r = 0; r < 4; ++r) {
      int row = m0 + wv * 16 + (lane >> 4) * 4 + r;
      int col = n0 + nt * 16 + lh;
      Cout[(size_t)b * 262144 + (size_t)row * 512 + col] = f2bf(acc[nt][r]);
    }
  }
}

static __device__ __forceinline__ void accum8v(float* a, float hk, u32x4 v) {
  unsigned u0 = v[0], u1 = v[1], u2 = v[2], u3 = v[3];
  a[0] += hk * __builtin_bit_cast(float, u0 << 16);
  a[1] += hk * __builtin_bit_cast(float, u0 & 0xffff0000u);
  a[2] += hk * __builtin_bit_cast(float, u1 << 16);
  a[3] += hk * __builtin_bit_cast(float, u1 & 0xffff0000u);
  a[4] += hk * __builtin_bit_cast(float, u2 << 16);
  a[5] += hk * __builtin_bit_cast(float, u2 & 0xffff0000u);
  a[6] += hk * __builtin_bit_cast(float, u3 << 16);
  a[7] += hk * __builtin_bit_cast(float, u3 & 0xffff0000u);
}

// ---------------------------------------------------------------------------
// k_scan5: 512-step scan; za/ra register-resident (asm-pinned), va in LDS.
// Grid = 256 WGs x 512 thr (1 WG/CU).  WG g: batch b = g>>2, col block
// w = g&3 (cols [w*128, w*128+128)).  Thread t: chunk = t&15 (8-col group),
// ph = t>>4 in [0,32) (k = ph + 32j, j in [0,16)).
// Exchange: pub[2][64][4][80] u32 (64 data dwords = 128 bf16 cols + tag at
// [64]).  Producer: data -> vmcnt(0) -> tag = tm+1 (MALL bypass).  Consumer:
// per-wave region spin, then load.  (R7/R8-verified scheme, unchanged.)
// Reduction: intra-wave __shfl_xor(16/32) collapses the 4 ph/wave, lanes
// 0..15 stage 24 floats/chunk to part[8][16][28]; 384 threads finish.
// ---------------------------------------------------------------------------
__global__ __launch_bounds__(512, 2) void k_scan5(
    const unsigned short* __restrict__ Az,   // [64][512][512] bf16 (row=k, col=out)
    const unsigned short* __restrict__ Ar,
    const unsigned short* __restrict__ Ah,
    const unsigned short* __restrict__ ZRx,  // [T*64][1024] bf16
    const unsigned short* __restrict__ Hx,   // [T*64][512] bf16
    const float* __restrict__ mask,          // [T*64]
    unsigned* __restrict__ pub,              // [2][64][4][80] u32
    float* out)
{
  const int g = blockIdx.x;
  const int b = g >> 2;
  const int w = g & 3;
  const int c0 = w * 128;
  const int t = threadIdx.x;
  const int chunk = t & 15;
  const int ph = t >> 4;                 // [0,32)
  const int wv = t >> 6, lane = t & 63;

  __shared__ unsigned short va_lds[512][136];  // Ah slice, 272B row stride
  __shared__ float hs[512];
  __shared__ float part[8][16][28];            // [wave][chunk][3*8], 16B-aligned rows
  __shared__ float red[384];                   // [mat*128 + col]

  // ---- one-time A preload ----
  const size_t abase = (size_t)b * 262144 + (size_t)ph * 512 + c0 + chunk * 8;
  u32x4 za[16], ra[16];
  #pragma unroll
  for (int j = 0; j < 16; ++j) {
    za[j] = *(const u32x4*)(Az + abase + (size_t)j * 32 * 512);
    ra[j] = *(const u32x4*)(Ar + abase + (size_t)j * 32 * 512);
  }
  // pin: asm outputs cannot be rematerialized -> must stay in VGPRs
  #pragma unroll
  for (int j = 0; j < 16; ++j)
    asm volatile("" : "+v"(za[j]), "+v"(ra[j]));
  #pragma unroll
  for (int j = 0; j < 16; ++j) {
    u32x4 v = *(const u32x4*)(Ah + abase + (size_t)j * 32 * 512);
    *(u32x4*)(&va_lds[ph + 32 * j][chunk * 8]) = v;
  }
  __syncthreads();

  unsigned* pubB0 = pub + (size_t)b * 320;         // parity 0: [4][80]
  unsigned* pubB1 = pub + (size_t)(64 + b) * 320;  // parity 1

  float hold0 = 0.f, hold1 = 0.f;  // master h (f32), cols c0+2t, c0+2t+1 (t<64)

  for (int tm = 0; tm < T_LEN; ++tm) {
    unsigned* pubC = (tm & 1) ? pubB1 : pubB0;   // consume (state after tm)
    unsigned* pubP = (tm & 1) ? pubB0 : pubB1;   // produce (state after tm+1)
    const size_t itb = (size_t)tm * BATCH + b;

    // gate-operand prefetch (cached loads; overlap with spin)
    unsigned p_zx = 0, p_rx = 0, p_hx = 0; float g_m = 0.f;
    if (t < 64) {
      int gc = c0 + 2 * t;
      p_zx = *(const unsigned*)(ZRx + itb * 1024 + gc);
      p_rx = *(const unsigned*)(ZRx + itb * 1024 + 512 + gc);
      p_hx = *(const unsigned*)(Hx + itb * 512 + gc);
      g_m  = mask[itb];
    }
    // per-wave region spin + h load (wave-uniform tag address)
    if (t < 256) {
      const unsigned* tagp = pubC + (t >> 6) * 80 + 64;
      while ((int)__hip_atomic_load(tagp, __ATOMIC_RELAXED, __HIP_MEMORY_SCOPE_AGENT) < tm)
        ;
      unsigned v = __hip_atomic_load(pubC + (t >> 6) * 80 + (t & 63),
                                     __ATOMIC_RELAXED, __HIP_MEMORY_SCOPE_AGENT);
      float2 hv;
      hv.x = bf2f((unsigned short)(v & 0xffffu));
      hv.y = bf2f((unsigned short)(v >> 16));
      *(float2*)(&hs[2 * t]) = hv;
    }
    __syncthreads();

    // GEMV: za/ra from registers, va from LDS, h from LDS.
    float az[8] = {0,0,0,0,0,0,0,0};
    float ar[8] = {0,0,0,0,0,0,0,0};
    float av[8] = {0,0,0,0,0,0,0,0};
    #pragma unroll
    for (int j = 0; j < 16; ++j) {
      float hk = hs[ph + 32 * j];
      accum8v(az, hk, za[j]);
      accum8v(ar, hk, ra[j]);
      u32x4 vv = *(const u32x4*)(&va_lds[ph + 32 * j][chunk * 8]);
      accum8v(av, hk, vv);
    }
    // intra-wave reduce over the 4 ph values per wave (xor lanes 16, 32)
    #pragma unroll
    for (int e = 0; e < 8; ++e) {
      az[e] += __shfl_xor(az[e], 16); az[e] += __shfl_xor(az[e], 32);
      ar[e] += __shfl_xor(ar[e], 16); ar[e] += __shfl_xor(ar[e], 32);
      av[e] += __shfl_xor(av[e], 16); av[e] += __shfl_xor(av[e], 32);
    }
    if (lane < 16) {
      #pragma unroll
      for (int e = 0; e < 8; ++e) {
        part[wv][chunk][e]      = az[e];
        part[wv][chunk][8 + e]  = ar[e];
        part[wv][chunk][16 + e] = av[e];
      }
    }
    __syncthreads();

    // final reduction: 384 threads, one (mat,col) output each, 8 adds
    if (t < 384) {
      int m = t >> 7, c = t & 127;
      int ch = c >> 3, e = m * 8 + (c & 7);
      float s = 0.f;
      #pragma unroll
      for (int p = 0; p < 8; ++p) s += part[p][ch][e];
      red[(m << 7) + c] = s;
    }
    __syncthreads();

    // gates + publish: wave 0, 2 cols per thread
    if (t < 64) {
      int c = 2 * t;
      float z0 = sigmoid_f(red[c]       + bf2f((unsigned short)(p_zx & 0xffffu)));
      float z1 = sigmoid_f(red[c + 1]   + bf2f((unsigned short)(p_zx >> 16)));
      float r0 = sigmoid_f(red[128 + c] + bf2f((unsigned short)(p_rx & 0xffffu)));
      float r1 = sigmoid_f(red[129 + c] + bf2f((unsigned short)(p_rx >> 16)));
      float hv0 = tanh_f(bf2f((unsigned short)(p_hx & 0xffffu)) + r0 * red[256 + c]);
      float hv1 = tanh_f(bf2f((unsigned short)(p_hx >> 16))     + r1 * red[257 + c]);
      float hn0 = (1.f - z0) * hv0 + z0 * hold0;
      float hn1 = (1.f - z1) * hv1 + z1 * hold1;
      hn0 = g_m * hn0 + (1.f - g_m) * hold0;
      hn1 = g_m * hn1 + (1.f - g_m) * hold1;
      hold0 = hn0; hold1 = hn1;
      // publish first (critical path), out-stores after the tag
      unsigned pk = (unsigned)f2bf(hn0) | ((unsigned)f2bf(hn1) << 16);
      __hip_atomic_store(pubP + w * 80 + t, pk,
                         __ATOMIC_RELAXED, __HIP_MEMORY_SCOPE_AGENT);
      asm volatile("s_waitcnt vmcnt(0)" ::: "memory");
      if (t == 0)
        __hip_atomic_store(pubP + w * 80 + 64, (unsigned)(tm + 1),
                           __ATOMIC_RELAXED, __HIP_MEMORY_SCOPE_AGENT);
      float2 o; o.x = hn0; o.y = hn1;
      *(float2*)(out + itb * 512 + c0 + c) = o;
      if (tm == T_LEN - 1)
        *(float2*)(out + (size_t)T_LEN * BATCH * 512 + (size_t)b * 512 + c0 + c) = o;
    }
    // waves 1..7 run ahead to the next step's spin; hs/part overwrite is
    // gated by the post-hs __syncthreads, which wave 0 joins after publish.
  }
}

// ---------------------------------------------------------------------------
extern "C" void kernel_launch(void* const* d_in, const int* in_sizes, int n_in,
                              void* d_out, int out_size, void* d_ws, size_t ws_size,
                              hipStream_t stream) {
  (void)in_sizes; (void)n_in; (void)out_size; (void)ws_size;
  const float* x        = (const float*)d_in[0];
  const float* topic    = (const float*)d_in[1];
  const float* mask     = (const float*)d_in[2];
  const float* W_x2zr   = (const float*)d_in[3];
  const float* W_tp2zrx = (const float*)d_in[4];
  const float* W_xtp2z  = (const float*)d_in[5];
  const float* b_xtp2z  = (const float*)d_in[6];
  const float* W_xtp2r  = (const float*)d_in[7];
  const float* b_xtp2r  = (const float*)d_in[8];
  const float* W_h2zr   = (const float*)d_in[9];
  const float* W_tp2zrh = (const float*)d_in[10];
  const float* W_htp2z  = (const float*)d_in[11];
  const float* W_htp2r  = (const float*)d_in[12];
  const float* W_x2h    = (const float*)d_in[13];
  const float* W_tp2hx  = (const float*)d_in[14];
  const float* W_xtp2h  = (const float*)d_in[15];
  const float* b_xtp2h  = (const float*)d_in[16];
  const float* W_h2h    = (const float*)d_in[17];
  const float* W_tp2hh  = (const float*)d_in[18];
  const float* W_htp2h  = (const float*)d_in[19];
  float* out = (float*)d_out;

  // ---- workspace carve (~194 MiB) ----
  char* w = (char*)d_ws;
  unsigned* pub = (unsigned*)w;      w += (size_t)2 * 64 * 4 * 80 * 4;  // 160 KB
  float* tzx = (float*)w;           w += (size_t)BATCH * 1024 * 4;
  float* tzh = (float*)w;           w += (size_t)BATCH * 1024 * 4;
  float* thx = (float*)w;           w += (size_t)BATCH * 512 * 4;
  float* thh = (float*)w;           w += (size_t)BATCH * 512 * 4;
  unsigned short* ZRxtp = (unsigned short*)w; w += (size_t)T_LEN * BATCH * 1024 * 2; // 64 MiB
  unsigned short* Hxtp  = (unsigned short*)w; w += (size_t)T_LEN * BATCH * 512 * 2;  // 32 MiB
  unsigned short* SCR   = (unsigned short*)w; w += (size_t)T_LEN * BATCH * 1024 * 2; // 64 MiB
  unsigned short* AhM   = (unsigned short*)w; w += (size_t)BATCH * 512 * 512 * 2;    // 32 MiB
  // SCR: phase-1 staging (ZRs, then Xhs), afterwards Az|Ar (2 x 32 MiB).
  unsigned short* ZRs = SCR;
  unsigned short* Xhs = SCR;
  unsigned short* AzM = SCR;
  unsigned short* ArM = SCR + (size_t)BATCH * 512 * 512;

  const int M = T_LEN * BATCH;  // 32768

  // pub zeroed: tags = 0 ("0 steps complete"), data = 0 (h0 = 0).
  hipMemsetAsync(pub, 0, (size_t)2 * 64 * 4 * 80 * 4, stream);

  // ---- phase 1: topic projections + x-side GEMM chain ----
  k_topic<<<BATCH, 256, 0, stream>>>(topic, W_tp2zrx, W_tp2zrh, W_tp2hx, W_tp2hh,
                                     tzx, tzh, thx, thh);
  gemm64<0, true, true><<<dim3(1024/64, M/64), 256, 0, stream>>>(
      x, DIN, W_x2zr, 1024, tzx, 1024, nullptr, ZRs, 1024, DIN);
  gemm64<1, false, true><<<dim3(512/64, M/64), 256, 0, stream>>>(
      ZRs, 1024, W_xtp2z, 512, nullptr, 0, b_xtp2z, ZRxtp, 1024, 512);
  gemm64<1, false, true><<<dim3(512/64, M/64), 256, 0, stream>>>(
      ZRs + 512, 1024, W_xtp2r, 512, nullptr, 0, b_xtp2r, ZRxtp + 512, 1024, 512);
  gemm64<0, true, true><<<dim3(512/64, M/64), 256, 0, stream>>>(
      x, DIN, W_x2h, 512, thx, 512, nullptr, Xhs, 512, DIN);
  gemm64<1, false, true><<<dim3(512/64, M/64), 256, 0, stream>>>(
      Xhs, 512, W_xtp2h, 512, nullptr, 0, b_xtp2h, Hxtp, 512, 512);

  // ---- combined per-batch recurrent matrices (overwrite SCR after use) ----
  k_comb<<<dim3(8, 8, 64), 256, 0, stream>>>(W_h2zr, 1024,   0, W_htp2z, tzh, 1024,   0, AzM);
  k_comb<<<dim3(8, 8, 64), 256, 0, stream>>>(W_h2zr, 1024, 512, W_htp2r, tzh, 1024, 512, ArM);
  k_comb<<<dim3(8, 8, 64), 256, 0, stream>>>(W_h2h,   512,   0, W_htp2h, thh,  512,   0, AhM);

  // ---- phase 2: register+LDS-resident GEMV scan, 256 WGs (1/CU) ----
  k_scan5<<<256, 512, 0, stream>>>(AzM, ArM, AhM, ZRxtp, Hxtp, mask,
                                   pub, out);
}

// Round 7
// 4180.213 us; speedup vs baseline: 3.8366x; 2.7631x over previous
//
#include <hip/hip_runtime.h>
#include <stdint.h>
#include <stddef.h>

// TPGRUCell forward, MI355X gfx950.
// R5: combined per-batch recurrent matrices (Az/Ar/Ah) -> per-batch GEMV scan.
// R6: 512 WGs, L2-resident A.  R7: fused tag-publish exchange -> k_scan3,
// 3.10 ms scan (PROVEN BEST - restored verbatim this round).
// R8/R9: VGPR-residency for A failed twice (allocator remats/spills pinned
// loads; FETCH shows per-step re-stream).  Abandoned.
// R10 (this round): phase 1 was ~1.08 ms at ~143 TF on 64x64 tiles.
// Replace gemm64 with gemm128: 128x128 tile, BK=32, 4 waves, 4x4 16x16
// fragments/wave -- a direct scale-up of the verified gemm64 conventions.
// Inputs pre-converted once: x -> bf16 (k_cvt, aliases AhM region), weights
// -> bf16 [n][k] (k_tr).  No new builtins.

#define T_LEN 512
#define BATCH 64
#define DIN   512
#define DH    512
#define DT    128

typedef __attribute__((ext_vector_type(8))) short short8;
typedef __attribute__((ext_vector_type(4))) float f32x4;

static __device__ __forceinline__ float bf2f(unsigned short u) {
  unsigned v = ((unsigned)u) << 16;
  return __builtin_bit_cast(float, v);
}
static __device__ __forceinline__ unsigned short f2bf(float f) {
  unsigned v = __builtin_bit_cast(unsigned, f);
  unsigned r = (v + 0x7fffu + ((v >> 16) & 1u)) >> 16;
  return (unsigned short)r;
}
static __device__ __forceinline__ float sigmoid_f(float x) {
  return 1.f / (1.f + __expf(-x));
}
static __device__ __forceinline__ float tanh_f(float x) {
  float e = __expf(-2.f * fabsf(x));
  float t = (1.f - e) / (1.f + e);
  return copysignf(t, x);
}

// ---------------------------------------------------------------------------
// k_cvt: f32 -> bf16, 8 elems/thread/iter, grid-stride.
// ---------------------------------------------------------------------------
__global__ __launch_bounds__(256) void k_cvt(const float* __restrict__ src,
                                             unsigned short* __restrict__ dst,
                                             int n8) {
  for (int idx = blockIdx.x * 256 + threadIdx.x; idx < n8; idx += gridDim.x * 256) {
    const float4* s = (const float4*)src + 2 * (size_t)idx;
    float4 a = s[0], b = s[1];
    unsigned short d[8];
    d[0] = f2bf(a.x); d[1] = f2bf(a.y); d[2] = f2bf(a.z); d[3] = f2bf(a.w);
    d[4] = f2bf(b.x); d[5] = f2bf(b.y); d[6] = f2bf(b.z); d[7] = f2bf(b.w);
    *(uint4*)(dst + (size_t)idx * 8) = *(const uint4*)d;
  }
}

// ---------------------------------------------------------------------------
// k_tr: dst[n][k] (bf16) = src[k][n] (f32); K,N multiples of 32. LDS-tiled.
// (verified R0-R3)
// ---------------------------------------------------------------------------
__global__ __launch_bounds__(256) void k_tr(const float* __restrict__ src,
                                            unsigned short* __restrict__ dst,
                                            int K, int N) {
  __shared__ float t[32][33];
  const int tx = threadIdx.x & 31, ty = threadIdx.x >> 5;  // 32 x 8
  const int k0 = blockIdx.y * 32, n0 = blockIdx.x * 32;
  for (int i = ty; i < 32; i += 8)
    t[i][tx] = src[(size_t)(k0 + i) * N + n0 + tx];
  __syncthreads();
  for (int i = ty; i < 32; i += 8)
    dst[(size_t)(n0 + i) * K + k0 + tx] = f2bf(t[tx][i]);
}

// ---------------------------------------------------------------------------
// k_topic: the four topic@W projections, all f32.
// ---------------------------------------------------------------------------
__global__ __launch_bounds__(256) void k_topic(
    const float* __restrict__ topic,
    const float* __restrict__ Wzx,  // [128][1024]
    const float* __restrict__ Wzh,  // [128][1024]
    const float* __restrict__ Whx,  // [128][512]
    const float* __restrict__ Whh,  // [128][512]
    float* __restrict__ tzx, float* __restrict__ tzh,
    float* __restrict__ thx, float* __restrict__ thh)
{
  const int b = blockIdx.x;
  __shared__ float tp[DT];
  if (threadIdx.x < DT) tp[threadIdx.x] = topic[b * DT + threadIdx.x];
  __syncthreads();
  for (int c = threadIdx.x; c < 3072; c += 256) {
    const float* wp; float* op; int ld, cc;
    if (c < 1024)      { wp = Wzx; ld = 1024; cc = c;        op = &tzx[b*1024 + cc]; }
    else if (c < 2048) { wp = Wzh; ld = 1024; cc = c - 1024; op = &tzh[b*1024 + cc]; }
    else if (c < 2560) { wp = Whx; ld = 512;  cc = c - 2048; op = &thx[b*512  + cc]; }
    else               { wp = Whh; ld = 512;  cc = c - 2560; op = &thh[b*512  + cc]; }
    float acc = 0.f;
    #pragma unroll 4
    for (int k = 0; k < DT; ++k) acc += tp[k] * wp[(size_t)k * ld + cc];
    *op = acc;
  }
}

// ---------------------------------------------------------------------------
// gemm128 (phase 1): C(bf16) = A(bf16 [M][lda]) @ B  with B given as
// BT(bf16 [N][ldb]) = B^T.  128x128 tile, BK=32, 256 thr (4 waves, 2x2 of
// 64x64, 4x4 16x16x32 fragments each).  Fragment conventions identical to
// the verified gemm64 (A[m][k], B^T[n][k], C col=lane&15 row=quad*4+r).
// EPI==0: C *= rs[(row&63)*ldrs+col]; EPI==1: C += bias[col].
// ---------------------------------------------------------------------------
template<int EPI>
__global__ __launch_bounds__(256) void gemm128(
    const unsigned short* __restrict__ A, int lda,
    const unsigned short* __restrict__ BT, int ldb,
    const float* __restrict__ rs, int ldrs,
    const float* __restrict__ bias,
    unsigned short* __restrict__ C, int ldc, int K)
{
  __shared__ unsigned short As[128][48];   // 96B row stride (16B-multiple)
  __shared__ unsigned short Bs[128][48];
  const int tid = threadIdx.x;
  const int n0 = blockIdx.x * 128;
  const int m0 = blockIdx.y * 128;
  const int wv = tid >> 6, lane = tid & 63;
  const int lh = lane & 15, quad = lane >> 4, q8 = quad * 8;
  const int wr = wv >> 1, wc = wv & 1;        // 2x2 wave grid of 64x64
  const int srow = tid >> 1, scol = (tid & 1) * 16;  // staging: row + 16-col half

  f32x4 acc[4][4] = {};

  for (int k0 = 0; k0 < K; k0 += 32) {
    uint4 a4[2], b4[2];
    {
      const unsigned short* ap = A  + (size_t)(m0 + srow) * lda + k0 + scol;
      const unsigned short* bp = BT + (size_t)(n0 + srow) * ldb + k0 + scol;
      a4[0] = ((const uint4*)ap)[0]; a4[1] = ((const uint4*)ap)[1];
      b4[0] = ((const uint4*)bp)[0]; b4[1] = ((const uint4*)bp)[1];
    }
    __syncthreads();   // previous tile fully consumed
    *(uint4*)(&As[srow][scol])     = a4[0];
    *(uint4*)(&As[srow][scol + 8]) = a4[1];
    *(uint4*)(&Bs[srow][scol])     = b4[0];
    *(uint4*)(&Bs[srow][scol + 8]) = b4[1];
    __syncthreads();
    short8 af[4], bf[4];
    #pragma unroll
    for (int i = 0; i < 4; ++i) {
      af[i] = *(const short8*)(&As[wr * 64 + i * 16 + lh][q8]);
      bf[i] = *(const short8*)(&Bs[wc * 64 + i * 16 + lh][q8]);
    }
    #pragma unroll
    for (int i = 0; i < 4; ++i)
      #pragma unroll
      for (int j = 0; j < 4; ++j)
        acc[i][j] = __builtin_amdgcn_mfma_f32_16x16x32_bf16(af[i], bf[j], acc[i][j], 0, 0, 0);
  }

  #pragma unroll
  for (int i = 0; i < 4; ++i)
    #pragma unroll
    for (int j = 0; j < 4; ++j)
      #pragma unroll
      for (int r = 0; r < 4; ++r) {
        int row = m0 + wr * 64 + i * 16 + quad * 4 + r;
        int col = n0 + wc * 64 + j * 16 + lh;
        float v = acc[i][j][r];
        if (EPI == 0) v *= rs[(size_t)(row & 63) * ldrs + col];
        else          v += bias[col];
        C[(size_t)row * ldc + col] = f2bf(v);
      }
}

// ---------------------------------------------------------------------------
// k_comb: per-batch combined matrix  C_b[i][c] = sum_k W1[i][off1+k] *
//         S[b][offS+k] * W2[k][c].   Grid (8, 8, 64), 256 thr, K = 512.
// (verified R2+)
// ---------------------------------------------------------------------------
__global__ __launch_bounds__(256) void k_comb(
    const float* __restrict__ W1, int ld1, int off1,  // [512][ld1]
    const float* __restrict__ W2,                     // [512][512]
    const float* __restrict__ S, int ldS, int offS,   // [64][ldS]
    unsigned short* __restrict__ Cout)                // [64][512][512] bf16
{
  __shared__ unsigned short As[64][48];
  __shared__ unsigned short Bs[64][48];
  const int tid = threadIdx.x;
  const int n0 = blockIdx.x * 64;
  const int m0 = blockIdx.y * 64;
  const int b  = blockIdx.z;
  const int wv = tid >> 6, lane = tid & 63;
  const int lh = lane & 15, q8 = (lane >> 4) * 8;
  const int arow = tid >> 2, acol = (tid & 3) * 8;
  const int brow = tid >> 3, bcol = (tid & 7) * 8;
  const float* sv = S + (size_t)b * ldS + offS;
  f32x4 acc[4] = {{0,0,0,0},{0,0,0,0},{0,0,0,0},{0,0,0,0}};

  for (int k0 = 0; k0 < 512; k0 += 32) {
    unsigned short av[8], bv[8];
    {
      const float* p = W1 + (size_t)(m0 + arow) * ld1 + off1 + k0 + acol;
      float4 a = ((const float4*)p)[0], c2 = ((const float4*)p)[1];
      av[0]=f2bf(a.x); av[1]=f2bf(a.y); av[2]=f2bf(a.z); av[3]=f2bf(a.w);
      av[4]=f2bf(c2.x); av[5]=f2bf(c2.y); av[6]=f2bf(c2.z); av[7]=f2bf(c2.w);
    }
    {
      float sk = sv[k0 + brow];
      const float* p = W2 + (size_t)(k0 + brow) * 512 + n0 + bcol;
      float4 a = ((const float4*)p)[0], c2 = ((const float4*)p)[1];
      bv[0]=f2bf(a.x*sk); bv[1]=f2bf(a.y*sk); bv[2]=f2bf(a.z*sk); bv[3]=f2bf(a.w*sk);
      bv[4]=f2bf(c2.x*sk); bv[5]=f2bf(c2.y*sk); bv[6]=f2bf(c2.z*sk); bv[7]=f2bf(c2.w*sk);
    }
    __syncthreads();
    *(uint4*)(&As[arow][acol]) = *(const uint4*)av;
    #pragma unroll
    for (int i = 0; i < 8; ++i) Bs[bcol + i][brow] = bv[i];
    __syncthreads();
    short8 af = *(const short8*)(&As[wv * 16 + lh][q8]);
    #pragma unroll
    for (int nt = 0; nt < 4; ++nt) {
      short8 bf = *(const short8*)(&Bs[nt * 16 + lh][q8]);
      acc[nt] = __builtin_amdgcn_mfma_f32_16x16x32_bf16(af, bf, acc[nt], 0, 0, 0);
    }
  }

  #pragma unroll
  for (int nt = 0; nt < 4; ++nt) {
    #pragma unroll
    for (int r = 0; r < 4; ++r) {
      int row = m0 + wv * 16 + (lane >> 4) * 4 + r;
      int col = n0 + nt * 16 + lh;
      Cout[(size_t)b * 262144 + (size_t)row * 512 + col] = f2bf(acc[nt][r]);
    }
  }
}

static __device__ __forceinline__ void accum8(float* a, float hk, uint4 v) {
  unsigned u0 = v.x, u1 = v.y, u2 = v.z, u3 = v.w;
  a[0] += hk * __builtin_bit_cast(float, u0 << 16);
  a[1] += hk * __builtin_bit_cast(float, u0 & 0xffff0000u);
  a[2] += hk * __builtin_bit_cast(float, u1 << 16);
  a[3] += hk * __builtin_bit_cast(float, u1 & 0xffff0000u);
  a[4] += hk * __builtin_bit_cast(float, u2 << 16);
  a[5] += hk * __builtin_bit_cast(float, u2 & 0xffff0000u);
  a[6] += hk * __builtin_bit_cast(float, u3 << 16);
  a[7] += hk * __builtin_bit_cast(float, u3 & 0xffff0000u);
}

// ---------------------------------------------------------------------------
// k_scan3 (R7-verified, verbatim): 512-step scan via per-batch GEMV on
// combined matrices.  Grid = 512 WGs x 512 thr.  WG g: batch b = g>>3,
// col block w = g&7 (cols [w*64, w*64+64)).
// Exchange: pub[2][64][8][64] u32 regions (32 h-dwords bf16x2 + tag at [32],
// 256B stride). Producer: data stores -> vmcnt(0) -> tag = tm+1 (all MALL
// bypass). Consumer step tm: spin 8 tags >= tm, sync, load data.
// ---------------------------------------------------------------------------
__global__ __launch_bounds__(512) void k_scan3(
    const unsigned short* __restrict__ Az,   // [64][512][512] bf16 (row=k, col=out)
    const unsigned short* __restrict__ Ar,
    const unsigned short* __restrict__ Ah,
    const unsigned short* __restrict__ ZRx,  // [T*64][1024] bf16
    const unsigned short* __restrict__ Hx,   // [T*64][512] bf16
    const float* __restrict__ mask,          // [T*64]
    unsigned* __restrict__ pub,              // [2][64][8][64] u32
    float* out)
{
  const int g = blockIdx.x;
  const int b = g >> 3;
  const int w = g & 7;
  const int c0 = w * 64;
  const int t = threadIdx.x;
  const int chunk = t & 7;
  const int ph = t >> 3;                 // [0,64)
  __shared__ float hs[512];
  __shared__ float part[64][8][25];      // [ph][chunk][3*8], padded stride 25
  __shared__ float red[192];             // reduced sums: [gate*64 + col]

  const size_t mbase = (size_t)b * 262144 + (size_t)ph * 512 + c0 + chunk * 8;
  const unsigned short* pz0 = Az + mbase;
  const unsigned short* pr0 = Ar + mbase;
  const unsigned short* pv0 = Ah + mbase;

  unsigned* pubB0 = pub + (size_t)b * 512;           // parity 0: [8][64]
  unsigned* pubB1 = pub + (size_t)(64 + b) * 512;    // parity 1

  float hold = 0.f;  // master h (f32) for col c0+t, threads t<64
  for (int tm = 0; tm < T_LEN; ++tm) {
    unsigned* pubC = (tm & 1) ? pubB1 : pubB0;   // consume (state after tm steps)
    unsigned* pubP = (tm & 1) ? pubB0 : pubB1;   // produce (state after tm+1)
    const size_t itb = (size_t)tm * BATCH + b;

    // gate-operand prefetch (HBM stream; hides under peer skew/spin)
    float g_zx = 0.f, g_rx = 0.f, g_hx = 0.f, g_m = 0.f;
    if (t < 64) {
      int gc = c0 + t;
      g_zx = bf2f(ZRx[itb * 1024 + gc]);
      g_rx = bf2f(ZRx[itb * 1024 + 512 + gc]);
      g_hx = bf2f(Hx[itb * 512 + gc]);
      g_m  = mask[itb];
    }
    // spin: lanes 0..7 poll the 8 region tags of this parity
    if (t < 8) {
      const unsigned* tagp = pubC + t * 64 + 32;
      while ((int)__hip_atomic_load(tagp, __ATOMIC_RELAXED, __HIP_MEMORY_SCOPE_AGENT) < tm)
        ;
    }
    __syncthreads();
    // h data -> LDS (bypass read; bf16x2 -> f32)
    if (t < 256) {
      unsigned v = __hip_atomic_load(pubC + (t >> 5) * 64 + (t & 31),
                                     __ATOMIC_RELAXED, __HIP_MEMORY_SCOPE_AGENT);
      int col = (t >> 5) * 64 + (t & 31) * 2;
      hs[col]     = bf2f((unsigned short)(v & 0xffffu));
      hs[col + 1] = bf2f((unsigned short)(v >> 16));
    }
    __syncthreads();

    // GEMV partials: 8 k's per thread (fully unrolled), 8 cols, 3 matrices
    float az[8] = {0,0,0,0,0,0,0,0};
    float ar[8] = {0,0,0,0,0,0,0,0};
    float av[8] = {0,0,0,0,0,0,0,0};
    #pragma unroll
    for (int j = 0; j < 8; ++j) {
      float hk = hs[ph + 64 * j];
      uint4 vz = *(const uint4*)(pz0 + (size_t)j * 64 * 512);
      uint4 vr = *(const uint4*)(pr0 + (size_t)j * 64 * 512);
      uint4 vv = *(const uint4*)(pv0 + (size_t)j * 64 * 512);
      accum8(az, hk, vz);
      accum8(ar, hk, vr);
      accum8(av, hk, vv);
    }
    #pragma unroll
    for (int e = 0; e < 8; ++e) {
      part[ph][chunk][e]      = az[e];
      part[ph][chunk][8 + e]  = ar[e];
      part[ph][chunk][16 + e] = av[e];
    }
    __syncthreads();

    // distributed reduction: 192 threads, one (gate,col) output each
    if (t < 192) {
      int c = t & 63;
      int ch = c >> 3;
      int e  = (t >> 6) * 8 + (c & 7);
      float s = 0.f;
      #pragma unroll 16
      for (int p = 0; p < 64; ++p) s += part[p][ch][e];
      red[t] = s;
    }
    __syncthreads();

    // gates + publish: wave 0 only (no trailing workgroup barrier)
    if (t < 64) {
      float z  = sigmoid_f(red[t] + g_zx);
      float r  = sigmoid_f(red[64 + t] + g_rx);
      float hv = tanh_f(g_hx + r * red[128 + t]);
      float hnew = (1.f - z) * hv + z * hold;
      hnew = g_m * hnew + (1.f - g_m) * hold;
      hold = hnew;
      int gc = c0 + t;
      out[itb * 512 + gc] = hnew;
      if (tm == T_LEN - 1)
        out[(size_t)T_LEN * BATCH * 512 + (size_t)b * 512 + gc] = hnew;
      // pack 64 bf16 cols into 32 dwords via wave shuffles, publish + tag
      int hb = (int)f2bf(hnew);
      unsigned lo = (unsigned)__shfl(hb, 2 * t);
      unsigned hi = (unsigned)__shfl(hb, 2 * t + 1);
      if (t < 32)
        __hip_atomic_store(pubP + w * 64 + t, lo | (hi << 16),
                           __ATOMIC_RELAXED, __HIP_MEMORY_SCOPE_AGENT);
      asm volatile("s_waitcnt vmcnt(0)" ::: "memory");
      if (t == 0)
        __hip_atomic_store(pubP + w * 64 + 32, (unsigned)(tm + 1),
                           __ATOMIC_RELAXED, __HIP_MEMORY_SCOPE_AGENT);
    }
    // waves 1..7 run ahead; they block at the next spin's __syncthreads,
    // which wave 0 joins only after publishing.
  }
}

// ---------------------------------------------------------------------------
extern "C" void kernel_launch(void* const* d_in, const int* in_sizes, int n_in,
                              void* d_out, int out_size, void* d_ws, size_t ws_size,
                              hipStream_t stream) {
  (void)in_sizes; (void)n_in; (void)out_size; (void)ws_size;
  const float* x        = (const float*)d_in[0];
  const float* topic    = (const float*)d_in[1];
  const float* mask     = (const float*)d_in[2];
  const float* W_x2zr   = (const float*)d_in[3];
  const float* W_tp2zrx = (const float*)d_in[4];
  const float* W_xtp2z  = (const float*)d_in[5];
  const float* b_xtp2z  = (const float*)d_in[6];
  const float* W_xtp2r  = (const float*)d_in[7];
  const float* b_xtp2r  = (const float*)d_in[8];
  const float* W_h2zr   = (const float*)d_in[9];
  const float* W_tp2zrh = (const float*)d_in[10];
  const float* W_htp2z  = (const float*)d_in[11];
  const float* W_htp2r  = (const float*)d_in[12];
  const float* W_x2h    = (const float*)d_in[13];
  const float* W_tp2hx  = (const float*)d_in[14];
  const float* W_xtp2h  = (const float*)d_in[15];
  const float* b_xtp2h  = (const float*)d_in[16];
  const float* W_h2h    = (const float*)d_in[17];
  const float* W_tp2hh  = (const float*)d_in[18];
  const float* W_htp2h  = (const float*)d_in[19];
  float* out = (float*)d_out;

  // ---- workspace carve (~196 MiB) ----
  char* w = (char*)d_ws;
  unsigned* pub = (unsigned*)w;      w += (size_t)2 * 64 * 8 * 64 * 4;  // 256 KB
  float* tzx = (float*)w;           w += (size_t)BATCH * 1024 * 4;
  float* tzh = (float*)w;           w += (size_t)BATCH * 1024 * 4;
  float* thx = (float*)w;           w += (size_t)BATCH * 512 * 4;
  float* thh = (float*)w;           w += (size_t)BATCH * 512 * 4;
  unsigned short* ZRxtp = (unsigned short*)w; w += (size_t)T_LEN * BATCH * 1024 * 2; // 64 MiB
  unsigned short* Hxtp  = (unsigned short*)w; w += (size_t)T_LEN * BATCH * 512 * 2;  // 32 MiB
  unsigned short* SCR   = (unsigned short*)w; w += (size_t)T_LEN * BATCH * 1024 * 2; // 64 MiB
  unsigned short* AhM   = (unsigned short*)w; w += (size_t)BATCH * 512 * 512 * 2;    // 32 MiB
  unsigned short* WzrT  = (unsigned short*)w; w += (size_t)1024 * 512 * 2;           // 1 MiB
  unsigned short* WzT   = (unsigned short*)w; w += (size_t)512 * 512 * 2;
  unsigned short* WrT   = (unsigned short*)w; w += (size_t)512 * 512 * 2;
  unsigned short* WxhT  = (unsigned short*)w; w += (size_t)512 * 512 * 2;
  unsigned short* WhpT  = (unsigned short*)w; w += (size_t)512 * 512 * 2;
  // SCR: phase-1 staging (ZRs, then Xhs), afterwards Az|Ar (2 x 32 MiB).
  // AhM: xb (bf16 x, 32 MiB) during phase 1, then Ah (written after last xb use).
  unsigned short* ZRs = SCR;
  unsigned short* Xhs = SCR;
  unsigned short* AzM = SCR;
  unsigned short* ArM = SCR + (size_t)BATCH * 512 * 512;
  unsigned short* xb  = AhM;

  const int M = T_LEN * BATCH;  // 32768

  // pub zeroed: tags = 0 ("0 steps complete"), data = 0 (h0 = 0).
  hipMemsetAsync(pub, 0, (size_t)2 * 64 * 8 * 64 * 4, stream);

  // ---- pre-converts: x -> bf16; weights -> bf16 [n][k] ----
  k_cvt<<<2048, 256, 0, stream>>>(x, xb, (int)((size_t)M * DIN / 8));
  k_tr<<<dim3(1024/32, 512/32), 256, 0, stream>>>(W_x2zr,  WzrT, 512, 1024);
  k_tr<<<dim3( 512/32, 512/32), 256, 0, stream>>>(W_xtp2z, WzT,  512,  512);
  k_tr<<<dim3( 512/32, 512/32), 256, 0, stream>>>(W_xtp2r, WrT,  512,  512);
  k_tr<<<dim3( 512/32, 512/32), 256, 0, stream>>>(W_x2h,   WxhT, 512,  512);
  k_tr<<<dim3( 512/32, 512/32), 256, 0, stream>>>(W_xtp2h, WhpT, 512,  512);

  // ---- phase 1: topic projections + x-side GEMM chain (128x128 tiles) ----
  k_topic<<<BATCH, 256, 0, stream>>>(topic, W_tp2zrx, W_tp2zrh, W_tp2hx, W_tp2hh,
                                     tzx, tzh, thx, thh);
  gemm128<0><<<dim3(1024/128, M/128), 256, 0, stream>>>(
      xb, DIN, WzrT, 512, tzx, 1024, nullptr, ZRs, 1024, DIN);
  gemm128<1><<<dim3(512/128, M/128), 256, 0, stream>>>(
      ZRs, 1024, WzT, 512, nullptr, 0, b_xtp2z, ZRxtp, 1024, 512);
  gemm128<1><<<dim3(512/128, M/128), 256, 0, stream>>>(
      ZRs + 512, 1024, WrT, 512, nullptr, 0, b_xtp2r, ZRxtp + 512, 1024, 512);
  gemm128<0><<<dim3(512/128, M/128), 256, 0, stream>>>(
      xb, DIN, WxhT, 512, thx, 512, nullptr, Xhs, 512, DIN);
  gemm128<1><<<dim3(512/128, M/128), 256, 0, stream>>>(
      Xhs, 512, WhpT, 512, nullptr, 0, b_xtp2h, Hxtp, 512, 512);

  // ---- combined per-batch recurrent matrices (overwrite SCR / xb after use) ----
  k_comb<<<dim3(8, 8, 64), 256, 0, stream>>>(W_h2zr, 1024,   0, W_htp2z, tzh, 1024,   0, AzM);
  k_comb<<<dim3(8, 8, 64), 256, 0, stream>>>(W_h2zr, 1024, 512, W_htp2r, tzh, 1024, 512, ArM);
  k_comb<<<dim3(8, 8, 64), 256, 0, stream>>>(W_h2h,   512,   0, W_htp2h, thh,  512,   0, AhM);

  // ---- phase 2: per-batch GEMV scan, 64 batches x 8 WGs (R7-proven) ----
  k_scan3<<<512, 512, 0, stream>>>(AzM, ArM, AhM, ZRxtp, Hxtp, mask,
                                   pub, out);
}